// Round 3
// baseline (1284.731 us; speedup 1.0000x reference)
//
#include <hip/hip_runtime.h>
#include <cstdint>
#include <cstddef>

#define HD    1024
#define SLOTS 272
#define MEMS  256
#define BATCH 8
#define TT    4096
#define RR    (BATCH*TT)
#define RANKC 10

#define GAMMA 0.92f
#define BETA  0.08f
#define PTS   0.4f

// packed fp32 (v_pk_fma_f32 / v_pk_mul_f32 on gfx950): halves VALU issue count
// in the single-wave scan.
typedef float f32x2 __attribute__((ext_vector_type(2)));
#define PKFMA(a, b, c) __builtin_elementwise_fma((a), (b), (c))

// ---------------------------------------------------------------------------
// DPP wave64 sum-allreduce primitives.
// ---------------------------------------------------------------------------
#define DPP_ADD(v, ctrl, rmask)                                                   \
    v += __int_as_float(__builtin_amdgcn_update_dpp(                              \
        0, __float_as_int(v), (ctrl), (rmask), 0xf, true))

__device__ __forceinline__ float wave_sum_bcast(float v)
{
    DPP_ADD(v, 0xB1,  0xf);   // + lane^1
    DPP_ADD(v, 0x4E,  0xf);   // + lane^2
    DPP_ADD(v, 0x141, 0xf);   // row_half_mirror
    DPP_ADD(v, 0x140, 0xf);   // row_mirror
    DPP_ADD(v, 0x142, 0xa);   // row_bcast15
    DPP_ADD(v, 0x143, 0xc);   // row_bcast31 (lane 63 = total)
    return __int_as_float(__builtin_amdgcn_readlane(__float_as_int(v), 63));
}

// three interleaved reduce chains: pipelines the DPP latency 3-wide.
__device__ __forceinline__ void wave_sum3(float& a, float& b, float& c)
{
#define L3(ctrl, rmask)                                                           \
    DPP_ADD(a, ctrl, rmask); DPP_ADD(b, ctrl, rmask); DPP_ADD(c, ctrl, rmask);
    L3(0xB1, 0xf) L3(0x4E, 0xf) L3(0x141, 0xf)
    L3(0x140, 0xf) L3(0x142, 0xa) L3(0x143, 0xc)
#undef L3
    a = __int_as_float(__builtin_amdgcn_readlane(__float_as_int(a), 63));
    b = __int_as_float(__builtin_amdgcn_readlane(__float_as_int(b), 63));
    c = __int_as_float(__builtin_amdgcn_readlane(__float_as_int(c), 63));
}

// ---------------------------------------------------------------------------
// prep: per-slot constants (unchanged).
// ---------------------------------------------------------------------------
__global__ void prep_kernel(const float* __restrict__ t0re, const float* __restrict__ t0im,
                            const float* __restrict__ eta_raw,
                            const float* __restrict__ trot, const float* __restrict__ w_r,
                            const float* __restrict__ bgate,
                            const float* __restrict__ eps_scale, const float* __restrict__ pred_scale,
                            const float* __restrict__ eps_diag, const float* __restrict__ pred_diag,
                            float* __restrict__ consts, int* __restrict__ flags)
{
    __shared__ float red[MEMS];
    const int s = threadIdx.x;  // 256 threads
    const float tr = t0re[s], ti = t0im[s];
    red[s] = tr * tr + ti * ti;
    __syncthreads();
    for (int off = 128; off > 0; off >>= 1) {
        if (s < off) red[s] += red[s + off];
        __syncthreads();
    }
    const float nrm = sqrtf(fmaxf(red[0], 1e-16f));
    const float eta = log1pf(expf(eta_raw[0]));
    const float rc = cosf(trot[s]), rs = sinf(trot[s]);
    const float c1 = GAMMA + eta * eps_diag[s];
    const float c2 = PTS * pred_diag[s];
    consts[0 * MEMS + s] = 1.0f / (1.0f + expf(-w_r[s]));
    consts[1 * MEMS + s] = 1.0f / (1.0f + expf(-bgate[s]));
    consts[2 * MEMS + s] = c1 * rc - c2 * rs;   // A
    consts[3 * MEMS + s] = c1 * rs + c2 * rc;   // B
    consts[4 * MEMS + s] = tr / nrm;
    consts[5 * MEMS + s] = ti / nrm;
    consts[6 * MEMS + s] = rc;
    consts[7 * MEMS + s] = rs;
    if (s == 0) {
        consts[8 * MEMS] = eta;
        int f1 = 0, f2 = 0;
        for (int k = 0; k < RANKC; ++k) {
            if (eps_scale[k]  != 0.0f) f1 = 1;
            if (pred_scale[k] != 0.0f) f2 = 1;
        }
        flags[0] = f1;
        flags[1] = f2;
    }
}

// ---------------------------------------------------------------------------
// proj: M(R x 256) = X(R x 1024) * Q,  Q[k][n] = basis[k*272 + n].
// 64(M) x 256(N=full width) tile, 256 threads, 8x8 microtile (split 4+4 col
// fragments at nt*4 and 128+nt*4 -> stride-16B conflict-free ds_read_b128).
// Full-width N tile means X is fetched from HBM exactly ONCE (was 4x).
// ---------------------------------------------------------------------------
__global__ __launch_bounds__(256) void proj_kernel(const float* __restrict__ x,
                                                   const float* __restrict__ basis,
                                                   float* __restrict__ M)
{
    __shared__ float As[16][64];    // [k][m]
    __shared__ float Bs[16][260];   // [k][n], pad 260 (mult of 4: keeps 16B align)
    const int tid  = threadIdx.x;
    const int row0 = blockIdx.x * 64;
    const int mt = tid >> 5;        // 0..7
    const int nt = tid & 31;        // 0..31
    const int ar = tid >> 2;        // 0..63  (A staging row)
    const int ak = (tid & 3) * 4;   // 0,4,8,12
    const int bk = tid >> 4;        // 0..15  (B staging k)
    const int bn = (tid & 15) * 16; // 0..240
    float acc[2][2][4][4] = {};
    for (int k0 = 0; k0 < HD; k0 += 16) {
        {
            const float4 av = *(const float4*)&x[(size_t)(row0 + ar) * HD + k0 + ak];
            As[ak + 0][ar] = av.x; As[ak + 1][ar] = av.y;
            As[ak + 2][ar] = av.z; As[ak + 3][ar] = av.w;
#pragma unroll
            for (int c = 0; c < 4; ++c) {
                const float4 bv = *(const float4*)&basis[(size_t)(k0 + bk) * SLOTS + bn + c * 4];
                *(float4*)&Bs[bk][bn + c * 4] = bv;
            }
        }
        __syncthreads();
#pragma unroll
        for (int kk = 0; kk < 16; ++kk) {
            const float4 a0 = *(const float4*)&As[kk][mt * 4];
            const float4 a1 = *(const float4*)&As[kk][32 + mt * 4];
            const float4 b0 = *(const float4*)&Bs[kk][nt * 4];
            const float4 b1 = *(const float4*)&Bs[kk][128 + nt * 4];
            const float av[2][4] = {{a0.x, a0.y, a0.z, a0.w}, {a1.x, a1.y, a1.z, a1.w}};
            const float bv[2][4] = {{b0.x, b0.y, b0.z, b0.w}, {b1.x, b1.y, b1.z, b1.w}};
#pragma unroll
            for (int p = 0; p < 2; ++p)
#pragma unroll
                for (int q = 0; q < 2; ++q)
#pragma unroll
                    for (int i = 0; i < 4; ++i)
#pragma unroll
                        for (int j = 0; j < 4; ++j)
                            acc[p][q][i][j] += av[p][i] * bv[q][j];
        }
        __syncthreads();
    }
#pragma unroll
    for (int p = 0; p < 2; ++p)
#pragma unroll
        for (int i = 0; i < 4; ++i) {
            const int r = row0 + p * 32 + mt * 4 + i;
#pragma unroll
            for (int q = 0; q < 2; ++q) {
                const float4 o = {acc[p][q][i][0], acc[p][q][i][1],
                                  acc[p][q][i][2], acc[p][q][i][3]};
                *(float4*)&M[(size_t)r * MEMS + q * 128 + nt * 4] = o;
            }
        }
}

// ---------------------------------------------------------------------------
// topk: per (b,t) row, find 8th-largest |m| (dup-counting), then mask the row
// IN PLACE: M[r,s] <- (|m|>=kth) ? BETA*m : 0.  (unchanged)
// ---------------------------------------------------------------------------
__global__ __launch_bounds__(64) void topk_kernel(float* __restrict__ M)
{
    const int r    = blockIdx.x;
    const int lane = threadIdx.x;
    float4 v = *(const float4*)&M[(size_t)r * MEMS + lane * 4];
    float vals[4] = {fabsf(v.x), fabsf(v.y), fabsf(v.z), fabsf(v.w)};
    float keep[4] = {vals[0], vals[1], vals[2], vals[3]};
    float kv = 0.0f;
#pragma unroll
    for (int it = 0; it < 8; ++it) {
        float lm = vals[0]; int li = 0;
#pragma unroll
        for (int j = 1; j < 4; ++j)
            if (vals[j] > lm) { lm = vals[j]; li = j; }
        float bm = lm; int bi = lane * 4 + li;
#pragma unroll
        for (int off = 1; off < 64; off <<= 1) {
            float om = __shfl_xor(bm, off);
            int   oi = __shfl_xor(bi, off);
            if (om > bm || (om == bm && oi < bi)) { bm = om; bi = oi; }
        }
        kv = bm;
        if ((bi >> 2) == lane) vals[bi & 3] = -1.0f;
    }
    float4 o;
    o.x = (keep[0] >= kv) ? BETA * v.x : 0.0f;
    o.y = (keep[1] >= kv) ? BETA * v.y : 0.0f;
    o.z = (keep[2] >= kv) ? BETA * v.z : 0.0f;
    o.w = (keep[3] >= kv) ? BETA * v.w : 0.0f;
    *(float4*)&M[(size_t)r * MEMS + lane * 4] = o;
}

// ---------------------------------------------------------------------------
// scan: one wave per batch, 4 slots/lane, all state in registers.
// CROSS-TERM DEFERRED NORM: w_t = ic1*L + wq with L = Ahat o w_{t-1},
// wq = wr o s_{t-2} + m_t.  ||w_t||^2 = ic1^2*RL + 2*ic1*RX + RW where
// RL=||L||^2, RX=Re<L,wq>, RW=||wq||^2 depend ONLY on w_{t-1}/q/m -- so the
// three interleaved DPP trees run OFF the carried chain (a full iteration of
// slack).  Carried scalar chain: ic_t = rsqrt(fmaf(fmaf(ic,RL,RX2),ic,RW))
// ~= 2 FMA + rsq.  Store path: s_{t-1} = w_{t-1}*ic1 (off-chain) is both the
// row written at t-1 and the next q.  Row 0 double-written; epilogue writes
// row TT-1.  Depth-16 prefetch ring (may read <=16 rows past slice: valid
// adjacent ws/d_out memory, values unused).
// ---------------------------------------------------------------------------
__global__ __launch_bounds__(64) void scan_kernel(const float* __restrict__ M,
                                                  const float* __restrict__ consts,
                                                  const int* __restrict__ flags,
                                                  const float* __restrict__ eps_fac,
                                                  const float* __restrict__ eps_scale,
                                                  const float* __restrict__ eps_diag,
                                                  const float* __restrict__ pred_fac,
                                                  const float* __restrict__ pred_scale,
                                                  const float* __restrict__ pred_diag,
                                                  float* __restrict__ Wout)
{
    const int b    = blockIdx.x;
    const int lane = threadIdx.x;
    const int s0   = lane * 4;
    const int general = flags[0] | flags[1];
    const size_t base = (size_t)b * TT * MEMS + s0;

    if (!general) {
        // ------------------ FAST PATH (3-tree off-chain norm) ------------------
        f32x2 wrg[2], A2[2], B2[2];
        f32x2 wre[2], wim[2], qre[2], qim[2];
        {
            const float4 w4 = *(const float4*)&consts[0 * MEMS + s0];
            const float4 a4 = *(const float4*)&consts[2 * MEMS + s0];
            const float4 b4 = *(const float4*)&consts[3 * MEMS + s0];
            const float4 r4 = *(const float4*)&consts[4 * MEMS + s0];
            const float4 i4 = *(const float4*)&consts[5 * MEMS + s0];
            wrg[0] = {w4.x, w4.y};  wrg[1] = {w4.z, w4.w};
            A2[0]  = {a4.x, a4.y};  A2[1]  = {a4.z, a4.w};
            B2[0]  = {b4.x, b4.y};  B2[1]  = {b4.z, b4.w};
            wre[0] = {r4.x, r4.y};  wre[1] = {r4.z, r4.w};   // w_{-1}=s_{-1} (unit)
            wim[0] = {i4.x, i4.y};  wim[1] = {i4.z, i4.w};
            qre[0] = wre[0]; qre[1] = wre[1];                // q = s_{-2} = tape0n
            qim[0] = wim[0]; qim[1] = wim[1];
        }
        float icv = 1.0f;  // ic_{-1}: ||tape0n|| = 1
        float4 mbuf[16];
#pragma unroll
        for (int j = 0; j < 16; ++j)
            mbuf[j] = *(const float4*)&M[base + (size_t)j * MEMS];
        for (int t0 = 0; t0 < TT; t0 += 16) {
#pragma unroll
            for (int j = 0; j < 16; ++j) {
                const int t = t0 + j;
                const float4 mc = mbuf[j];
                mbuf[j] = *(const float4*)&M[base + (size_t)(t + 16) * MEMS];
                // L = Ahat o w_{t-1}
                const f32x2 Lr0 = PKFMA(A2[0], wre[0], -(B2[0] * wim[0]));
                const f32x2 Li0 = PKFMA(B2[0], wre[0],  A2[0] * wim[0]);
                const f32x2 Lr1 = PKFMA(A2[1], wre[1], -(B2[1] * wim[1]));
                const f32x2 Li1 = PKFMA(B2[1], wre[1],  A2[1] * wim[1]);
                // wq = wr o q + m  (m real)
                const f32x2 m0 = {mc.x, mc.y};
                const f32x2 m1 = {mc.z, mc.w};
                const f32x2 Wr0 = PKFMA(wrg[0], qre[0], m0);
                const f32x2 Wi0 = wrg[0] * qim[0];
                const f32x2 Wr1 = PKFMA(wrg[1], qre[1], m1);
                const f32x2 Wi1 = wrg[1] * qim[1];
                // per-lane partials for the three reduces (all off-chain)
                f32x2 el = PKFMA(Li0, Li0, Lr0 * Lr0);
                el = PKFMA(Lr1, Lr1, el); el = PKFMA(Li1, Li1, el);
                float pl = el.x + el.y;                       // ||L||^2 partial
                f32x2 ex = PKFMA(Li0, Wi0, Lr0 * Wr0);
                ex = PKFMA(Lr1, Wr1, ex); ex = PKFMA(Li1, Wi1, ex);
                float px2 = (ex.x + ex.y) * 2.0f;             // 2*Re<L,wq> partial
                f32x2 ew = PKFMA(Wi0, Wi0, Wr0 * Wr0);
                ew = PKFMA(Wr1, Wr1, ew); ew = PKFMA(Wi1, Wi1, ew);
                float pw = ew.x + ew.y;                       // ||wq||^2 partial
                wave_sum3(pl, px2, pw);                       // -> RL, RX2, RW
                // store s_{t-1} = w_{t-1} * ic1  (off-chain; also next q)
                const f32x2 ic2 = {icv, icv};
                const f32x2 sr0 = wre[0] * ic2, si0 = wim[0] * ic2;
                const f32x2 sr1 = wre[1] * ic2, si1 = wim[1] * ic2;
                const int trow = t ? (t - 1) : 0;
                const float4 st4 = {sr0.x, sr0.y, sr1.x, sr1.y};
                *(float4*)&Wout[base + (size_t)trow * MEMS] = st4;
                // join: w_t = ic1*L + wq   (uses ic1 from previous iteration)
                const f32x2 w0r = PKFMA(ic2, Lr0, Wr0), w0i = PKFMA(ic2, Li0, Wi0);
                const f32x2 w1r = PKFMA(ic2, Lr1, Wr1), w1i = PKFMA(ic2, Li1, Wi1);
                // scalar chain: nn_t = (ic1*RL + RX2)*ic1 + RW ; ic_t = rsqrt
                const float nn = fmaf(fmaf(icv, pl, px2), icv, pw);
                icv = __builtin_amdgcn_rsqf(fmaxf(nn, 1e-16f));
                // rotate carries
                qre[0] = sr0; qim[0] = si0; qre[1] = sr1; qim[1] = si1;
                wre[0] = w0r; wim[0] = w0i; wre[1] = w1r; wim[1] = w1i;
            }
        }
        // epilogue: row TT-1 = w_{TT-1} * ic_{TT-1}
        {
            const float4 wq4 = {wre[0].x * icv, wre[0].y * icv,
                                wre[1].x * icv, wre[1].y * icv};
            *(float4*)&Wout[base + (size_t)(TT - 1) * MEMS] = wq4;
        }
        return;
    }

    // ------------------------ GENERAL PATH (unchanged) ------------------------
    float wr4[4], ur[4], ui[4], pr[4], pi[4];
    float rc4[4], rs4[4], ed4[4], pd4[4];
#pragma unroll
    for (int i = 0; i < 4; ++i) {
        wr4[i] = consts[0 * MEMS + s0 + i];
        ur[i]  = consts[4 * MEMS + s0 + i];
        ui[i]  = consts[5 * MEMS + s0 + i];
        pr[i] = ur[i]; pi[i] = ui[i];
        rc4[i] = consts[6 * MEMS + s0 + i];
        rs4[i] = consts[7 * MEMS + s0 + i];
        ed4[i] = eps_diag[s0 + i];
        pd4[i] = pred_diag[s0 + i];
    }
    const float eta  = consts[8 * MEMS];
    const int es_any = flags[0];
    const int ps_any = flags[1];
    float4 mbuf[4];
#pragma unroll
    for (int j = 0; j < 4; ++j)
        mbuf[j] = *(const float4*)&M[base + (size_t)j * MEMS];
    for (int t0 = 0; t0 < TT; t0 += 4) {
#pragma unroll
        for (int j = 0; j < 4; ++j) {
            const int t = t0 + j;
            const float4 mc = mbuf[j];
            mbuf[j] = *(const float4*)&M[base + (size_t)(t + 4) * MEMS];
            float rr[4], ri[4], nr[4], ni[4];
#pragma unroll
            for (int i = 0; i < 4; ++i) {
                rr[i] = ur[i] * rc4[i] - ui[i] * rs4[i];
                ri[i] = ur[i] * rs4[i] + ui[i] * rc4[i];
            }
            const float mv[4] = {mc.x, mc.y, mc.z, mc.w};
#pragma unroll
            for (int i = 0; i < 4; ++i) {
                nr[i] = GAMMA * rr[i] + wr4[i] * pr[i] + eta * ed4[i] * rr[i]
                        - PTS * pd4[i] * ri[i] + mv[i];   // mv already BETA*inj
                ni[i] = GAMMA * ri[i] + wr4[i] * pi[i] + eta * ed4[i] * ri[i]
                        + PTS * pd4[i] * rr[i];
            }
            if (es_any) {
#pragma unroll
                for (int k = 0; k < RANKC; ++k) {
                    float u[4], prj = 0.0f, pij = 0.0f;
#pragma unroll
                    for (int i = 0; i < 4; ++i) {
                        u[i] = eps_fac[(size_t)(s0 + i) * RANKC + k];
                        prj = fmaf(u[i], rr[i], prj);
                        pij = fmaf(u[i], ri[i], pij);
                    }
                    prj = wave_sum_bcast(prj);
                    pij = wave_sum_bcast(pij);
                    const float sc = eta * eps_scale[k];
#pragma unroll
                    for (int i = 0; i < 4; ++i) {
                        nr[i] = fmaf(sc * u[i], prj, nr[i]);
                        ni[i] = fmaf(sc * u[i], pij, ni[i]);
                    }
                }
            }
            if (ps_any) {
#pragma unroll
                for (int k = 0; k < RANKC; ++k) {
                    float u[4], qrj = 0.0f, qij = 0.0f;
#pragma unroll
                    for (int i = 0; i < 4; ++i) {
                        u[i] = pred_fac[(size_t)(s0 + i) * RANKC + k];
                        qrj = fmaf(u[i], rr[i], qrj);
                        qij = fmaf(u[i], ri[i], qij);
                    }
                    qrj = wave_sum_bcast(qrj);
                    qij = wave_sum_bcast(qij);
                    const float sc = PTS * pred_scale[k];
#pragma unroll
                    for (int i = 0; i < 4; ++i) {
                        nr[i] = fmaf(-sc * u[i], qij, nr[i]);
                        ni[i] = fmaf( sc * u[i], qrj, ni[i]);
                    }
                }
            }
            float ss = 0.0f;
#pragma unroll
            for (int i = 0; i < 4; ++i) ss = fmaf(nr[i], nr[i], fmaf(ni[i], ni[i], ss));
            ss = wave_sum_bcast(ss);
            const float inv = __builtin_amdgcn_rsqf(fmaxf(ss, 1e-16f));
#pragma unroll
            for (int i = 0; i < 4; ++i) {
                pr[i] = ur[i]; pi[i] = ui[i];
                ur[i] = nr[i] * inv; ui[i] = ni[i] * inv;
            }
            const float4 wq = {ur[0], ur[1], ur[2], ur[3]};
            *(float4*)&Wout[base + (size_t)t * MEMS] = wq;
        }
    }
}

// ---------------------------------------------------------------------------
// outp: Y = X + W * (alpha * bg[k] * basisT).  64(M) x 256(N) tile, 8x8
// microtile (split 4+4 col fragments).  N-tile 256 cuts W re-reads from 16x
// to 4x (512MB -> 128MB of HBM traffic).  W rows already normalized.
// ---------------------------------------------------------------------------
__global__ __launch_bounds__(256) void outp_kernel(const float* __restrict__ W,
                                                   const float* __restrict__ basis,
                                                   const float* __restrict__ x,
                                                   const float* __restrict__ alpha_p,
                                                   const float* __restrict__ consts,
                                                   float* __restrict__ y)
{
    __shared__ float As[16][64];    // [k][m]   (k = slot dim)
    __shared__ float Bs[16][260];   // [k][h]
    const int tid  = threadIdx.x;
    const int row0 = blockIdx.x * 64;
    const int col0 = blockIdx.y * 256;  // h block
    const int mt = tid >> 5;        // 0..7
    const int nt = tid & 31;        // 0..31
    const int ar = tid >> 2;        // 0..63
    const int ak = (tid & 3) * 4;   // 0,4,8,12
    const float alpha = alpha_p[0];
    const float* bgc  = consts + MEMS;
    float acc[2][2][4][4] = {};
    for (int k0 = 0; k0 < MEMS; k0 += 16) {
        {
            const float4 av = *(const float4*)&W[(size_t)(row0 + ar) * MEMS + k0 + ak];
            As[ak + 0][ar] = av.x; As[ak + 1][ar] = av.y;
            As[ak + 2][ar] = av.z; As[ak + 3][ar] = av.w;
            // B[k][h] = alpha*bg[k]*basis[(col0+h)*SLOTS + k]; thread owns h=tid
#pragma unroll
            for (int c = 0; c < 4; ++c) {
                const float4 bv  = *(const float4*)&basis[(size_t)(col0 + tid) * SLOTS + k0 + c * 4];
                const float4 bg4 = *(const float4*)&bgc[k0 + c * 4];
                Bs[c * 4 + 0][tid] = bv.x * (alpha * bg4.x);
                Bs[c * 4 + 1][tid] = bv.y * (alpha * bg4.y);
                Bs[c * 4 + 2][tid] = bv.z * (alpha * bg4.z);
                Bs[c * 4 + 3][tid] = bv.w * (alpha * bg4.w);
            }
        }
        __syncthreads();
#pragma unroll
        for (int kk = 0; kk < 16; ++kk) {
            const float4 a0 = *(const float4*)&As[kk][mt * 4];
            const float4 a1 = *(const float4*)&As[kk][32 + mt * 4];
            const float4 b0 = *(const float4*)&Bs[kk][nt * 4];
            const float4 b1 = *(const float4*)&Bs[kk][128 + nt * 4];
            const float av[2][4] = {{a0.x, a0.y, a0.z, a0.w}, {a1.x, a1.y, a1.z, a1.w}};
            const float bv[2][4] = {{b0.x, b0.y, b0.z, b0.w}, {b1.x, b1.y, b1.z, b1.w}};
#pragma unroll
            for (int p = 0; p < 2; ++p)
#pragma unroll
                for (int q = 0; q < 2; ++q)
#pragma unroll
                    for (int i = 0; i < 4; ++i)
#pragma unroll
                        for (int j = 0; j < 4; ++j)
                            acc[p][q][i][j] += av[p][i] * bv[q][j];
        }
        __syncthreads();
    }
#pragma unroll
    for (int p = 0; p < 2; ++p)
#pragma unroll
        for (int i = 0; i < 4; ++i) {
            const int r = row0 + p * 32 + mt * 4 + i;
#pragma unroll
            for (int q = 0; q < 2; ++q) {
                const size_t ro = (size_t)r * HD + col0 + q * 128 + nt * 4;
                const float4 xv = *(const float4*)&x[ro];
                const float4 o  = {xv.x + acc[p][q][i][0], xv.y + acc[p][q][i][1],
                                   xv.z + acc[p][q][i][2], xv.w + acc[p][q][i][3]};
                *(float4*)&y[ro] = o;
            }
        }
}

// ---------------------------------------------------------------------------
extern "C" void kernel_launch(void* const* d_in, const int* in_sizes, int n_in,
                              void* d_out, int out_size, void* d_ws, size_t ws_size,
                              hipStream_t stream)
{
    const float* x          = (const float*)d_in[0];
    const float* basis      = (const float*)d_in[1];
    const float* t0re       = (const float*)d_in[2];
    const float* t0im       = (const float*)d_in[3];
    const float* eta_raw    = (const float*)d_in[4];
    const float* alpha      = (const float*)d_in[5];
    const float* trot       = (const float*)d_in[6];
    const float* w_r        = (const float*)d_in[7];
    const float* bgate      = (const float*)d_in[8];
    const float* eps_fac    = (const float*)d_in[9];
    const float* eps_scale  = (const float*)d_in[10];
    const float* eps_diag   = (const float*)d_in[11];
    const float* pred_fac   = (const float*)d_in[12];
    const float* pred_scale = (const float*)d_in[13];
    const float* pred_diag  = (const float*)d_in[14];
    float* out = (float*)d_out;

    const size_t szM = (size_t)RR * MEMS * sizeof(float);  // 32 MB
    const size_t szW = szM;                                 // 32 MB
    const size_t szC = 16384;                               // consts + flags

    char* ws = (char*)d_ws;
    float *Mbuf, *Wbuf, *cbuf;
    if (ws_size >= szM + szW + szC) {
        Mbuf = (float*)(ws);
        Wbuf = (float*)(ws + szM);
        cbuf = (float*)(ws + szM + szW);
    } else {
        // fallback: stage M in d_out (consumed by topk+scan before outp rewrites it)
        Mbuf = (float*)d_out;
        Wbuf = (float*)(ws);
        cbuf = (float*)(ws + szW);
    }
    int* fbuf = (int*)(cbuf + 8 * MEMS + 16);

    prep_kernel<<<1, 256, 0, stream>>>(t0re, t0im, eta_raw, trot, w_r, bgate,
                                       eps_scale, pred_scale, eps_diag, pred_diag,
                                       cbuf, fbuf);
    proj_kernel<<<dim3(RR / 64, 1), 256, 0, stream>>>(x, basis, Mbuf);
    topk_kernel<<<RR, 64, 0, stream>>>(Mbuf);
    scan_kernel<<<BATCH, 64, 0, stream>>>(Mbuf, cbuf, fbuf,
                                          eps_fac, eps_scale, eps_diag,
                                          pred_fac, pred_scale, pred_diag,
                                          Wbuf);
    outp_kernel<<<dim3(RR / 64, HD / 256), 256, 0, stream>>>(Wbuf, basis, x, alpha,
                                                             cbuf, out);
}